// Round 9
// baseline (205.813 us; speedup 1.0000x reference)
//
#include <hip/hip_runtime.h>
#include <hip/hip_bf16.h>

// Problem constants
#define B_TOT  4096
#define M_TOT  65536
#define D_V    64
#define KD     96            // 64 (keys) + 32 (0.5*contexts); Q side pre-scaled by log2e
#define BQ     128           // q rows per block (4 waves x 32)
#define BN     64            // keys per inner tile
#define NQT    (B_TOT / BQ)  // 32
#define SHIFT2 23.0f         // fixed softmax shift in exp2 domain

using short8   = __attribute__((ext_vector_type(8))) short;
using floatx4  = __attribute__((ext_vector_type(4))) float;
using int4v    = __attribute__((ext_vector_type(4))) int;

static __device__ __forceinline__ unsigned short f2bf(float f) {
  return __builtin_bit_cast(unsigned short, __float2bfloat16(f));
}

// pack two f32 -> one dword of bf16 (lo = a, hi = b)
#if defined(__has_builtin)
#  if __has_builtin(__builtin_amdgcn_cvt_pk_bf16_f32)
#    define HAVE_CVT_PK_BF16 1
#  endif
#endif
static __device__ __forceinline__ int pack_bf16(float a, float b) {
#ifdef HAVE_CVT_PK_BF16
  typedef __bf16 bf16x2_t __attribute__((ext_vector_type(2)));
  bf16x2_t v = __builtin_amdgcn_cvt_pk_bf16_f32(a, b);
  return __builtin_bit_cast(int, v);
#else
  // truncation pack (bias cancels in softmax ratio; ~1-2 VALU ops)
  unsigned ua = __builtin_bit_cast(unsigned, a);
  unsigned ub = __builtin_bit_cast(unsigned, b);
  return (int)((ua >> 16) | (ub & 0xFFFF0000u));
#endif
}

static __device__ __forceinline__ floatx4 mfma16(short8 a, short8 b, floatx4 c) {
  return __builtin_amdgcn_mfma_f32_16x16x32_bf16(a, b, c, 0, 0, 0);
}

#define LOG2E 1.4426950408889634f

// ---- fused prep kernel ------------------------------------------------------
// blocks [0,1024): kc2   [1024,2048): vt2   [2048,3584): qc   [3584,3840): bias

#define NB_K 1024
#define NB_V 1024
#define NB_Q 1536
#define NB_B 256

__global__ __launch_bounds__(256) void
prep_all(const float* __restrict__ q, const float* __restrict__ ctx,
         const float* __restrict__ keys, const float* __restrict__ ctxs,
         const float* __restrict__ vals, const float* __restrict__ ts,
         const int* __restrict__ used,
         unsigned short* __restrict__ qc, unsigned short* __restrict__ kc2,
         unsigned short* __restrict__ vt2, float* __restrict__ bias)
{
  __shared__ float sbuf[64 * 65 + 64 * 33];
  const int bid = blockIdx.x;
  const int t = threadIdx.x;

  if (bid < NB_K) {
    // K+context in MFMA fragment-linear order (A-operand of S^T = K*Q^T):
    // kc2[g][c][lane][8], c = nt*3+s; elem = Kc[m=g*64+nt*16+(lane&15)][kk=s*32+(lane>>4)*8+j]
    float* lk = sbuf;               // [64][65]
    float* lx = sbuf + 64 * 65;     // [64][33]
    const int g = bid;
    const float* kb = keys + (size_t)g * 64 * 64;
    const float* xb = ctxs + (size_t)g * 64 * 32;
#pragma unroll
    for (int i = 0; i < 16; ++i) {
      int idx = i * 256 + t;
      lk[(idx >> 6) * 65 + (idx & 63)] = kb[idx];
    }
#pragma unroll
    for (int i = 0; i < 8; ++i) {
      int idx = i * 256 + t;
      lx[(idx >> 5) * 33 + (idx & 31)] = xb[idx];
    }
    __syncthreads();
    unsigned short* outp = kc2 + (size_t)g * 6144;
#pragma unroll
    for (int p = 0; p < 3; ++p) {
      int o = p * 2048 + t * 8;
      int c = o >> 9;
      int lane = (o >> 3) & 63;
      int lqq = lane >> 4, lcc = lane & 15;
      int nt = c / 3, s = c - nt * 3;
      int ml = nt * 16 + lcc;
      short8 v;
#pragma unroll
      for (int j = 0; j < 8; ++j) {
        int kk = s * 32 + lqq * 8 + j;
        float f = (kk < 64) ? lk[ml * 65 + kk] : lx[ml * 33 + (kk - 64)];
        v[j] = (short)f2bf(f);
      }
      *reinterpret_cast<short8*>(outp + o) = v;
    }
  } else if (bid < NB_K + NB_V) {
    // V fragment-linear (B-operand of P*V), with the key-permutation baked in
    // so the packed exp2 output IS the PV A-fragment:
    //   pi(lq*8+j) = (j<4) ? lq*4+j : 16 + lq*4 + (j-4)
    // vt2[g][c2][lane][8], c2 = h*4+nd;
    // elem = V[m = g*64 + h*32 + pi(lq*8+j)][d = nd*16+(lane&15)]
    float* lv = sbuf;               // [64][65]
    const int g = bid - NB_K;
    const float* vb = vals + (size_t)g * 64 * 64;
#pragma unroll
    for (int i = 0; i < 16; ++i) {
      int idx = i * 256 + t;
      lv[(idx >> 6) * 65 + (idx & 63)] = vb[idx];
    }
    __syncthreads();
    unsigned short* outp = vt2 + (size_t)g * 4096;
#pragma unroll
    for (int p = 0; p < 2; ++p) {
      int o = p * 2048 + t * 8;
      int c2 = o >> 9;
      int lane = (o >> 3) & 63;
      int lqq = lane >> 4, lcc = lane & 15;
      int h = c2 >> 2, nd = c2 & 3;
      short8 w;
#pragma unroll
      for (int j = 0; j < 8; ++j) {
        int mloc = h * 32 + ((j < 4) ? (lqq * 4 + j) : (16 + lqq * 4 + (j - 4)));
        w[j] = (short)f2bf(lv[mloc * 65 + nd * 16 + lcc]);
      }
      *reinterpret_cast<short8*>(outp + o) = w;
    }
  } else if (bid < NB_K + NB_V + NB_Q) {
    int tt = (bid - NB_K - NB_V) * 256 + t;     // 4096*96
    int b = tt / KD, j = tt % KD;
    float v = (j < 64) ? q[b * 64 + j] : 0.5f * ctx[b * 32 + (j - 64)];
    qc[tt] = f2bf(v * LOG2E);
  } else {
    int m = (bid - NB_K - NB_V - NB_Q) * 256 + t;
    bias[m] = used[m] ? (LOG2E * 0.3f * __expf(-0.1f * (1.0f - ts[m])) - SHIFT2) : -1e9f;
  }
}

// ---- flash attention main kernel -------------------------------------------
// grid (NQT, NC); block 256 = 4 waves; each wave owns 32 q rows (2 B-frags).
// K/V staged once per block-iter into double-buffered LDS (global_load_lds,
// width 16, one barrier/iter). S^T = K*Q^T; the packed exp2 output IS the PV
// A-fragment (V rows pre-permuted in prep) -> zero LDS for P.
// Row sums in VALU (per-lane partials + epilogue shfl_xor across quads).

template<int NC>
__global__ __launch_bounds__(256, 4) void
flash_kernel(const unsigned short* __restrict__ qc,
             const unsigned short* __restrict__ kc2,
             const unsigned short* __restrict__ vt2,
             const float* __restrict__ bias,
             float* __restrict__ opart, float* __restrict__ lpart)
{
  constexpr int MC  = M_TOT / NC;      // keys per block
  constexpr int NIT = MC / BN;
  __shared__ __align__(16) unsigned short lds_kv[2 * 10240];  // 40960 B
  const int qt    = blockIdx.x;
  const int chunk = blockIdx.y;
  const int tid   = threadIdx.x;
  const int w     = tid >> 6;
  const int lane  = tid & 63;
  const int lq    = lane >> 4;
  const int lc    = lane & 15;

  floatx4 zero; zero[0] = 0.f; zero[1] = 0.f; zero[2] = 0.f; zero[3] = 0.f;

  // Q fragments (B-operand): q-rows qt*128 + w*32 + a*16 + lc
  short8 qf[2][3];
#pragma unroll
  for (int a = 0; a < 2; ++a) {
    const unsigned short* qrp = qc + (size_t)(qt * BQ + w * 32 + a * 16 + lc) * KD + lq * 8;
    qf[a][0] = *reinterpret_cast<const short8*>(qrp);
    qf[a][1] = *reinterpret_cast<const short8*>(qrp + 32);
    qf[a][2] = *reinterpret_cast<const short8*>(qrp + 64);
  }

  const int g0 = chunk * (MC / 64);
  const float* bptr = bias + chunk * MC + lq * 4;

  // cooperative stage of one 64-key group: 20 x 1KB pieces, 5 per wave
  auto stage = [&](int it, int buf) {
    const unsigned short* kg = kc2 + (size_t)(g0 + it) * 6144;
    const unsigned short* vg = vt2 + (size_t)(g0 + it) * 4096;
    unsigned short* lb = lds_kv + buf * 10240;
#pragma unroll
    for (int j5 = 0; j5 < 5; ++j5) {
      int j = w + j5 * 4;
      const unsigned short* src = (j < 12) ? (kg + j * 512) : (vg + (j - 12) * 512);
      __builtin_amdgcn_global_load_lds(
          (const __attribute__((address_space(1))) void*)(src + lane * 8),
          (__attribute__((address_space(3))) void*)(lb + j * 512),
          16, 0, 0);
    }
  };

  floatx4 o[2][4];
#pragma unroll
  for (int a = 0; a < 2; ++a)
#pragma unroll
    for (int nd = 0; nd < 4; ++nd) o[a][nd] = zero;
  float lsum[2] = {0.f, 0.f};

  stage(0, 0);

#pragma unroll 1
  for (int it = 0; it < NIT; ++it) {
    __syncthreads();                 // stage(it) landed; prev-iter LDS reads done
    if (it + 1 < NIT) stage(it + 1, (it + 1) & 1);

    const unsigned short* lb = lds_kv + (it & 1) * 10240;

    // S^T = K*Q^T per 16-key tile; P packed in-register (PV A-frag layout)
    int4v pk[2][2];
#pragma unroll
    for (int nt = 0; nt < 4; ++nt) {
      short8 k0 = *reinterpret_cast<const short8*>(lb + (nt * 3 + 0) * 512 + lane * 8);
      short8 k1 = *reinterpret_cast<const short8*>(lb + (nt * 3 + 1) * 512 + lane * 8);
      short8 k2 = *reinterpret_cast<const short8*>(lb + (nt * 3 + 2) * 512 + lane * 8);
      floatx4 b4 = *reinterpret_cast<const floatx4*>(bptr + nt * 16);
#pragma unroll
      for (int a = 0; a < 2; ++a) {
        floatx4 acc = zero;
        acc = mfma16(k0, qf[a][0], acc);
        acc = mfma16(k1, qf[a][1], acc);
        acc = mfma16(k2, qf[a][2], acc);
        float p0 = __builtin_amdgcn_exp2f(acc[0] + b4[0]);
        float p1 = __builtin_amdgcn_exp2f(acc[1] + b4[1]);
        float p2 = __builtin_amdgcn_exp2f(acc[2] + b4[2]);
        float p3 = __builtin_amdgcn_exp2f(acc[3] + b4[3]);
        lsum[a] += (p0 + p1) + (p2 + p3);
        pk[a][nt >> 1][(nt & 1) * 2]     = pack_bf16(p0, p1);
        pk[a][nt >> 1][(nt & 1) * 2 + 1] = pack_bf16(p2, p3);
      }
    }
    // O += P * V (V frags from LDS, shared by both a-tiles)
#pragma unroll
    for (int nd = 0; nd < 4; ++nd) {
      short8 v0 = *reinterpret_cast<const short8*>(lb + 6144 + nd * 512 + lane * 8);
      short8 v1 = *reinterpret_cast<const short8*>(lb + 6144 + (4 + nd) * 512 + lane * 8);
#pragma unroll
      for (int a = 0; a < 2; ++a) {
        o[a][nd] = mfma16(__builtin_bit_cast(short8, pk[a][0]), v0, o[a][nd]);
        o[a][nd] = mfma16(__builtin_bit_cast(short8, pk[a][1]), v1, o[a][nd]);
      }
    }
    bptr += BN;
  }

  // epilogue: write partial O and l
  const int pb = qt * NC + chunk;
  float* op = opart + (size_t)pb * BQ * D_V;
#pragma unroll
  for (int a = 0; a < 2; ++a) {
    const int rbase = w * 32 + a * 16 + lq * 4;
#pragma unroll
    for (int nd = 0; nd < 4; ++nd)
#pragma unroll
      for (int r = 0; r < 4; ++r)
        op[(rbase + r) * D_V + nd * 16 + lc] = o[a][nd][r];
    // lsum[a]: this lane's key-partials for q=lc; combine the 4 lq groups
    float ls = lsum[a];
    ls += __shfl_xor(ls, 16, 64);
    ls += __shfl_xor(ls, 32, 64);
    if (lq == 0) lpart[(size_t)pb * BQ + w * 32 + a * 16 + lc] = ls;
  }
}

// ---- final reduction (float4-vectorized) ------------------------------------

template<int NC>
__global__ void reduce_out(const float* __restrict__ opart, const float* __restrict__ lpart,
                           float* __restrict__ out) {
  int t = blockIdx.x * 256 + threadIdx.x;   // 65536 float4s total
  int d4 = t & 15;
  int b = t >> 4;            // q-row 0..4095
  int qt = b >> 7, r = b & 127;
  const floatx4* op4 = reinterpret_cast<const floatx4*>(opart);
  floatx4 os; os[0] = 0.f; os[1] = 0.f; os[2] = 0.f; os[3] = 0.f;
  float ls = 0.f;
#pragma unroll
  for (int c = 0; c < NC; ++c) {
    int row = (qt * NC + c) * BQ + r;
    os += op4[(size_t)row * 16 + d4];
    ls += lpart[row];
  }
  float inv = 1.0f / ls;
  reinterpret_cast<floatx4*>(out)[t] = os * inv;
}

// ---- launcher ---------------------------------------------------------------

template<int NC>
static void launch_all(const float* query, const float* context, const float* keys,
                       const float* values, const float* contexts, const float* ts,
                       const int* used, float* out, char* ws, hipStream_t stream) {
  unsigned short* qc  = (unsigned short*)ws;  ws += (size_t)B_TOT * KD * 2;
  unsigned short* kc2 = (unsigned short*)ws;  ws += (size_t)M_TOT * KD * 2;
  unsigned short* vt2 = (unsigned short*)ws;  ws += (size_t)D_V * M_TOT * 2;
  float* bias  = (float*)ws;                  ws += (size_t)M_TOT * 4;
  float* opart = (float*)ws;                  ws += (size_t)NC * B_TOT * D_V * 4;
  float* lpart = (float*)ws;

  prep_all<<<NB_K + NB_V + NB_Q + NB_B, 256, 0, stream>>>(
      query, context, keys, contexts, values, ts, used, qc, kc2, vt2, bias);

  dim3 grid(NQT, NC);
  flash_kernel<NC><<<grid, 256, 0, stream>>>(qc, kc2, vt2, bias, opart, lpart);

  reduce_out<NC><<<(B_TOT * D_V / 4) / 256, 256, 0, stream>>>(opart, lpart, out);
}

extern "C" void kernel_launch(void* const* d_in, const int* in_sizes, int n_in,
                              void* d_out, int out_size, void* d_ws, size_t ws_size,
                              hipStream_t stream) {
  const float* query    = (const float*)d_in[0];
  const float* context  = (const float*)d_in[1];
  const float* keys     = (const float*)d_in[2];
  const float* values   = (const float*)d_in[3];
  const float* contexts = (const float*)d_in[4];
  const float* ts       = (const float*)d_in[5];
  const int*   used     = (const int*)d_in[6];
  float* out = (float*)d_out;
  char* ws = (char*)d_ws;

  const size_t fixed = (size_t)B_TOT * KD * 2 + (size_t)M_TOT * KD * 2 +
                       (size_t)D_V * M_TOT * 2 + (size_t)M_TOT * 4;
  const size_t need32 = fixed + 32ull * ((size_t)B_TOT * D_V * 4 + (size_t)B_TOT * 4);

  if (ws_size >= need32)
    launch_all<32>(query, context, keys, values, contexts, ts, used, out, ws, stream);
  else
    launch_all<16>(query, context, keys, values, contexts, ts, used, out, ws, stream);
}

// Round 10
// 190.844 us; speedup vs baseline: 1.0784x; 1.0784x over previous
//
#include <hip/hip_runtime.h>
#include <hip/hip_bf16.h>

// Problem constants
#define B_TOT  4096
#define M_TOT  65536
#define D_V    64
#define KD     96            // 64 (keys) + 32 (0.5*contexts); Q side pre-scaled by log2e
#define BQ     128           // q rows per block (4 waves x 32)
#define BN     64            // keys per inner tile
#define NQT    (B_TOT / BQ)  // 32
#define SHIFT2 23.0f         // fixed softmax shift in exp2 domain

using short8   = __attribute__((ext_vector_type(8))) short;
using floatx4  = __attribute__((ext_vector_type(4))) float;
using int4v    = __attribute__((ext_vector_type(4))) int;

static __device__ __forceinline__ unsigned short f2bf(float f) {
  return __builtin_bit_cast(unsigned short, __float2bfloat16(f));
}

// truncation pack: two f32 -> one dword of bf16 (lo=a, hi=b). ~2 VALU ops.
// Truncation bias cancels in the softmax ratio (verified R9: absmax 3.05e-5).
static __device__ __forceinline__ int pack_bf16(float a, float b) {
  unsigned ua = __builtin_bit_cast(unsigned, a);
  unsigned ub = __builtin_bit_cast(unsigned, b);
  return (int)((ua >> 16) | (ub & 0xFFFF0000u));
}

static __device__ __forceinline__ floatx4 mfma16(short8 a, short8 b, floatx4 c) {
  return __builtin_amdgcn_mfma_f32_16x16x32_bf16(a, b, c, 0, 0, 0);
}

#define LOG2E 1.4426950408889634f

// ---- fused prep kernel ------------------------------------------------------
// blocks [0,1024): kc2   [1024,2048): vt2   [2048,3584): qc   [3584,3840): bias

#define NB_K 1024
#define NB_V 1024
#define NB_Q 1536
#define NB_B 256

__global__ __launch_bounds__(256) void
prep_all(const float* __restrict__ q, const float* __restrict__ ctx,
         const float* __restrict__ keys, const float* __restrict__ ctxs,
         const float* __restrict__ vals, const float* __restrict__ ts,
         const int* __restrict__ used,
         unsigned short* __restrict__ qc, unsigned short* __restrict__ kc2,
         unsigned short* __restrict__ vt2, float* __restrict__ bias)
{
  __shared__ float sbuf[64 * 65 + 64 * 33];
  const int bid = blockIdx.x;
  const int t = threadIdx.x;

  if (bid < NB_K) {
    // K+context in MFMA fragment-linear order (A-operand of S^T = K*Q^T):
    // kc2[g][c][lane][8], c = nt*3+s; elem = Kc[m=g*64+nt*16+(lane&15)][kk=s*32+(lane>>4)*8+j]
    float* lk = sbuf;               // [64][65]
    float* lx = sbuf + 64 * 65;     // [64][33]
    const int g = bid;
    const float* kb = keys + (size_t)g * 64 * 64;
    const float* xb = ctxs + (size_t)g * 64 * 32;
#pragma unroll
    for (int i = 0; i < 16; ++i) {
      int idx = i * 256 + t;
      lk[(idx >> 6) * 65 + (idx & 63)] = kb[idx];
    }
#pragma unroll
    for (int i = 0; i < 8; ++i) {
      int idx = i * 256 + t;
      lx[(idx >> 5) * 33 + (idx & 31)] = xb[idx];
    }
    __syncthreads();
    unsigned short* outp = kc2 + (size_t)g * 6144;
#pragma unroll
    for (int p = 0; p < 3; ++p) {
      int o = p * 2048 + t * 8;
      int c = o >> 9;
      int lane = (o >> 3) & 63;
      int lqq = lane >> 4, lcc = lane & 15;
      int nt = c / 3, s = c - nt * 3;
      int ml = nt * 16 + lcc;
      short8 v;
#pragma unroll
      for (int j = 0; j < 8; ++j) {
        int kk = s * 32 + lqq * 8 + j;
        float f = (kk < 64) ? lk[ml * 65 + kk] : lx[ml * 33 + (kk - 64)];
        v[j] = (short)f2bf(f);
      }
      *reinterpret_cast<short8*>(outp + o) = v;
    }
  } else if (bid < NB_K + NB_V) {
    // V fragment-linear (B-operand of P*V), with the key-permutation baked in
    // so the packed exp2 output IS the PV A-fragment:
    //   pi(lq*8+j) = (j<4) ? lq*4+j : 16 + lq*4 + (j-4)
    // vt2[g][c2][lane][8], c2 = h*4+nd;
    // elem = V[m = g*64 + h*32 + pi(lq*8+j)][d = nd*16+(lane&15)]
    float* lv = sbuf;               // [64][65]
    const int g = bid - NB_K;
    const float* vb = vals + (size_t)g * 64 * 64;
#pragma unroll
    for (int i = 0; i < 16; ++i) {
      int idx = i * 256 + t;
      lv[(idx >> 6) * 65 + (idx & 63)] = vb[idx];
    }
    __syncthreads();
    unsigned short* outp = vt2 + (size_t)g * 4096;
#pragma unroll
    for (int p = 0; p < 2; ++p) {
      int o = p * 2048 + t * 8;
      int c2 = o >> 9;
      int lane = (o >> 3) & 63;
      int lqq = lane >> 4, lcc = lane & 15;
      int h = c2 >> 2, nd = c2 & 3;
      short8 w;
#pragma unroll
      for (int j = 0; j < 8; ++j) {
        int mloc = h * 32 + ((j < 4) ? (lqq * 4 + j) : (16 + lqq * 4 + (j - 4)));
        w[j] = (short)f2bf(lv[mloc * 65 + nd * 16 + lcc]);
      }
      *reinterpret_cast<short8*>(outp + o) = w;
    }
  } else if (bid < NB_K + NB_V + NB_Q) {
    int tt = (bid - NB_K - NB_V) * 256 + t;     // 4096*96
    int b = tt / KD, j = tt % KD;
    float v = (j < 64) ? q[b * 64 + j] : 0.5f * ctx[b * 32 + (j - 64)];
    qc[tt] = f2bf(v * LOG2E);
  } else {
    int m = (bid - NB_K - NB_V - NB_Q) * 256 + t;
    bias[m] = used[m] ? (LOG2E * 0.3f * __expf(-0.1f * (1.0f - ts[m])) - SHIFT2) : -1e9f;
  }
}

// ---- flash attention main kernel -------------------------------------------
// grid (NQT, NC); block 256 = 4 waves; each wave owns 32 q rows (2 B-frags).
// K/V staged per block-iter into double-buffered LDS (global_load_lds w=16).
// Software-pipelined: PV(it-1) runs BEFORE the barrier of iter it, using pk
// registers from the previous iteration and the still-valid other LDS buffer.
// This decouples PV from pack -> MFMA and VALU phases of different waves
// overlap instead of convoying. S^T = K*Q^T; packed exp2 output IS the PV
// A-fragment (V rows pre-permuted). Row sums via ones-MFMA.

template<int NC>
__global__ __launch_bounds__(256, 4) void
flash_kernel(const unsigned short* __restrict__ qc,
             const unsigned short* __restrict__ kc2,
             const unsigned short* __restrict__ vt2,
             const float* __restrict__ bias,
             float* __restrict__ opart, float* __restrict__ lpart)
{
  constexpr int MC  = M_TOT / NC;      // keys per block
  constexpr int NIT = MC / BN;         // >= 2
  __shared__ __align__(16) unsigned short lds_kv[2 * 10240];  // 40960 B
  const int qt    = blockIdx.x;
  const int chunk = blockIdx.y;
  const int tid   = threadIdx.x;
  const int w     = tid >> 6;
  const int lane  = tid & 63;
  const int lq    = lane >> 4;
  const int lc    = lane & 15;

  floatx4 zero; zero[0] = 0.f; zero[1] = 0.f; zero[2] = 0.f; zero[3] = 0.f;

  // Q fragments (B-operand): q-rows qt*128 + w*32 + a*16 + lc
  short8 qf[2][3];
#pragma unroll
  for (int a = 0; a < 2; ++a) {
    const unsigned short* qrp = qc + (size_t)(qt * BQ + w * 32 + a * 16 + lc) * KD + lq * 8;
    qf[a][0] = *reinterpret_cast<const short8*>(qrp);
    qf[a][1] = *reinterpret_cast<const short8*>(qrp + 32);
    qf[a][2] = *reinterpret_cast<const short8*>(qrp + 64);
  }

  short8 ones;
#pragma unroll
  for (int i = 0; i < 8; ++i) ones[i] = (short)0x3F80;  // bf16 1.0

  const int g0 = chunk * (MC / 64);
  const float* bptr = bias + chunk * MC + lq * 4;

  // cooperative stage of one 64-key group: 20 x 1KB pieces, 5 per wave
  auto stage = [&](int it, int buf) {
    const unsigned short* kg = kc2 + (size_t)(g0 + it) * 6144;
    const unsigned short* vg = vt2 + (size_t)(g0 + it) * 4096;
    unsigned short* lb = lds_kv + buf * 10240;
#pragma unroll
    for (int j5 = 0; j5 < 5; ++j5) {
      int j = w + j5 * 4;
      const unsigned short* src = (j < 12) ? (kg + j * 512) : (vg + (j - 12) * 512);
      __builtin_amdgcn_global_load_lds(
          (const __attribute__((address_space(1))) void*)(src + lane * 8),
          (__attribute__((address_space(3))) void*)(lb + j * 512),
          16, 0, 0);
    }
  };

  floatx4 o[2][4];
#pragma unroll
  for (int a = 0; a < 2; ++a)
#pragma unroll
    for (int nd = 0; nd < 4; ++nd) o[a][nd] = zero;
  floatx4 lacc[2] = {zero, zero};
  int4v pk[2][2];

  // QK + exp2 + pack phase (fills pk; accumulates row sums via ones-MFMA)
  auto qk_phase = [&](const unsigned short* lb, const float* bp) {
#pragma unroll
    for (int nt = 0; nt < 4; ++nt) {
      short8 k0 = *reinterpret_cast<const short8*>(lb + (nt * 3 + 0) * 512 + lane * 8);
      short8 k1 = *reinterpret_cast<const short8*>(lb + (nt * 3 + 1) * 512 + lane * 8);
      short8 k2 = *reinterpret_cast<const short8*>(lb + (nt * 3 + 2) * 512 + lane * 8);
      floatx4 b4 = *reinterpret_cast<const floatx4*>(bp + nt * 16);
#pragma unroll
      for (int a = 0; a < 2; ++a) {
        floatx4 acc = zero;
        acc = mfma16(k0, qf[a][0], acc);
        acc = mfma16(k1, qf[a][1], acc);
        acc = mfma16(k2, qf[a][2], acc);
        float p0 = __builtin_amdgcn_exp2f(acc[0] + b4[0]);
        float p1 = __builtin_amdgcn_exp2f(acc[1] + b4[1]);
        float p2 = __builtin_amdgcn_exp2f(acc[2] + b4[2]);
        float p3 = __builtin_amdgcn_exp2f(acc[3] + b4[3]);
        pk[a][nt >> 1][(nt & 1) * 2]     = pack_bf16(p0, p1);
        pk[a][nt >> 1][(nt & 1) * 2 + 1] = pack_bf16(p2, p3);
      }
    }
#pragma unroll
    for (int a = 0; a < 2; ++a) {
      lacc[a] = mfma16(__builtin_bit_cast(short8, pk[a][0]), ones, lacc[a]);
      lacc[a] = mfma16(__builtin_bit_cast(short8, pk[a][1]), ones, lacc[a]);
    }
  };

  // PV phase for the pk currently in registers, V frags from given buffer
  auto pv_phase = [&](const unsigned short* lb) {
#pragma unroll
    for (int nd = 0; nd < 4; ++nd) {
      short8 v0 = *reinterpret_cast<const short8*>(lb + 6144 + nd * 512 + lane * 8);
      short8 v1 = *reinterpret_cast<const short8*>(lb + 6144 + (4 + nd) * 512 + lane * 8);
#pragma unroll
      for (int a = 0; a < 2; ++a) {
        o[a][nd] = mfma16(__builtin_bit_cast(short8, pk[a][0]), v0, o[a][nd]);
        o[a][nd] = mfma16(__builtin_bit_cast(short8, pk[a][1]), v1, o[a][nd]);
      }
    }
  };

  // prologue
  stage(0, 0);
  __syncthreads();                  // stage(0) landed
  stage(1, 1);
  qk_phase(lds_kv, bptr);
  bptr += BN;

#pragma unroll 1
  for (int it = 1; it < NIT; ++it) {
    // PV for iter it-1: buffer (it-1)&1 still valid (stage(it+1) not yet issued)
    pv_phase(lds_kv + ((it - 1) & 1) * 10240);
    __syncthreads();               // drains PV ds_reads + stage(it) vmcnt
    if (it + 1 < NIT) stage(it + 1, (it + 1) & 1);
    qk_phase(lds_kv + (it & 1) * 10240, bptr);
    bptr += BN;
  }
  pv_phase(lds_kv + ((NIT - 1) & 1) * 10240);

  // epilogue: write partial O and l
  const int pb = qt * NC + chunk;
  float* op = opart + (size_t)pb * BQ * D_V;
#pragma unroll
  for (int a = 0; a < 2; ++a) {
    const int rbase = w * 32 + a * 16 + lq * 4;
#pragma unroll
    for (int nd = 0; nd < 4; ++nd)
#pragma unroll
      for (int r = 0; r < 4; ++r)
        op[(rbase + r) * D_V + nd * 16 + lc] = o[a][nd][r];
    // lacc C-layout: lane (lq,lc) reg r holds l[q-row = lq*4+r] (same across lc)
    if (lc == 0) {
      float* lp = lpart + (size_t)pb * BQ;
#pragma unroll
      for (int r = 0; r < 4; ++r) lp[rbase + r] = lacc[a][r];
    }
  }
}

// ---- final reduction (float4-vectorized) ------------------------------------

template<int NC>
__global__ void reduce_out(const float* __restrict__ opart, const float* __restrict__ lpart,
                           float* __restrict__ out) {
  int t = blockIdx.x * 256 + threadIdx.x;   // 65536 float4s total
  int d4 = t & 15;
  int b = t >> 4;            // q-row 0..4095
  int qt = b >> 7, r = b & 127;
  const floatx4* op4 = reinterpret_cast<const floatx4*>(opart);
  floatx4 os; os[0] = 0.f; os[1] = 0.f; os[2] = 0.f; os[3] = 0.f;
  float ls = 0.f;
#pragma unroll
  for (int c = 0; c < NC; ++c) {
    int row = (qt * NC + c) * BQ + r;
    os += op4[(size_t)row * 16 + d4];
    ls += lpart[row];
  }
  float inv = 1.0f / ls;
  reinterpret_cast<floatx4*>(out)[t] = os * inv;
}

// ---- launcher ---------------------------------------------------------------

template<int NC>
static void launch_all(const float* query, const float* context, const float* keys,
                       const float* values, const float* contexts, const float* ts,
                       const int* used, float* out, char* ws, hipStream_t stream) {
  unsigned short* qc  = (unsigned short*)ws;  ws += (size_t)B_TOT * KD * 2;
  unsigned short* kc2 = (unsigned short*)ws;  ws += (size_t)M_TOT * KD * 2;
  unsigned short* vt2 = (unsigned short*)ws;  ws += (size_t)D_V * M_TOT * 2;
  float* bias  = (float*)ws;                  ws += (size_t)M_TOT * 4;
  float* opart = (float*)ws;                  ws += (size_t)NC * B_TOT * D_V * 4;
  float* lpart = (float*)ws;

  prep_all<<<NB_K + NB_V + NB_Q + NB_B, 256, 0, stream>>>(
      query, context, keys, contexts, values, ts, used, qc, kc2, vt2, bias);

  dim3 grid(NQT, NC);
  flash_kernel<NC><<<grid, 256, 0, stream>>>(qc, kc2, vt2, bias, opart, lpart);

  reduce_out<NC><<<(B_TOT * D_V / 4) / 256, 256, 0, stream>>>(opart, lpart, out);
}

extern "C" void kernel_launch(void* const* d_in, const int* in_sizes, int n_in,
                              void* d_out, int out_size, void* d_ws, size_t ws_size,
                              hipStream_t stream) {
  const float* query    = (const float*)d_in[0];
  const float* context  = (const float*)d_in[1];
  const float* keys     = (const float*)d_in[2];
  const float* values   = (const float*)d_in[3];
  const float* contexts = (const float*)d_in[4];
  const float* ts       = (const float*)d_in[5];
  const int*   used     = (const int*)d_in[6];
  float* out = (float*)d_out;
  char* ws = (char*)d_ws;

  const size_t fixed = (size_t)B_TOT * KD * 2 + (size_t)M_TOT * KD * 2 +
                       (size_t)D_V * M_TOT * 2 + (size_t)M_TOT * 4;
  const size_t need32 = fixed + 32ull * ((size_t)B_TOT * D_V * 4 + (size_t)B_TOT * 4);

  if (ws_size >= need32)
    launch_all<32>(query, context, keys, values, contexts, ts, used, out, ws, stream);
  else
    launch_all<16>(query, context, keys, values, contexts, ts, used, out, ws, stream);
}